// Round 12
// baseline (134.740 us; speedup 1.0000x reference)
//
#include <hip/hip_runtime.h>

#define FEAT_H 32
#define FEAT_W 110
#define NCELL (FEAT_H * FEAT_W) /* 3520 */
#define STRIDEPX 16
#define NB 8
#define NG 32
#define NANC 36
#define NC 4
#define A_TOTAL (NCELL * NANC) /* 126720 */

#define CPB 576              /* colpass: 36 anchor-templates x 16 lanes */

#define BLK 512              /* k_main threads/block (r9/r11 shape: best measured) */
#define BPI 31               /* blocks per image (15872/512) */
#define G2 (NB * BPI)        /* 248 blocks */
#define NPAIR 3960           /* (col,template) pairs per image = 110*36 */
#define UREAL 15840          /* real pair-slots per image = 3960*4 rowgroups */
#define NSLOT 8              /* rows per thread (rowgroup = 8 rows) */

__device__ __forceinline__ float smooth_l1(float x) {
    float ax = fabsf(x);
    return ax < 1.f ? 0.5f * ax * ax : ax - 0.5f;
}

// ws: colpart[256] u64 @0 (2 KB), acc[8] f32 @8192, done u32 @8224.

// LESSONS (rounds 2-11):
// (a) no min-waves arg to __launch_bounds__ (r2/r4: ~150 MB scratch spill).
// (b) ~90 us of e2e is the harness's 256 MiB workspace re-poison fills
//     (6.3 TB/s, their own roofline); k_main is the only lever; ~12 us of
//     k_main is dispatch ramp (248 blocks x ~47 ns).
// (c) BLK=512/BPI=31 is the proven shape (r10's 256-thr split regressed).
// (d) exact skips compound: x-skip (r9) + y-band skip (this round) — both
//     rely on "all inter=0 can never displace the inter=0 seed".
// (e) trans chains (lse exp/log, best rcp) are fixmap-independent: compute
//     them before the build barrier so their latency hides under it.

// Factorized column-max pass (r5, exact; unchanged).
__global__ __launch_bounds__(CPB) void k_colpass(
    const float* __restrict__ gt_boxes, const int* __restrict__ gt_valid,
    const float* __restrict__ anchors, unsigned long long* __restrict__ colpart,
    float* __restrict__ acc, unsigned* __restrict__ done) {
#pragma clang fp contract(off)
    __shared__ unsigned long long cand[NANC];
    const int tid = threadIdx.x;
    const int bg = blockIdx.x; // column (b*NG+g), 0..255
    if (bg == 0) { // ws is 0xAA-poisoned each call
        if (tid < 8) acc[tid] = 0.f;
        if (tid == 8) *done = 0u;
    }
    const int t = tid >> 4;    // anchor template 0..35
    const int lane = tid & 15; // 16 lanes per template
    const int valid = gt_valid[bg];
    const float g0 = gt_boxes[bg * 4 + 0], g1 = gt_boxes[bg * 4 + 1];
    const float g2 = gt_boxes[bg * 4 + 2], g3 = gt_boxes[bg * 4 + 3];
    const float ag = (g2 - g0 + 1.f) * (g3 - g1 + 1.f);
    const float* ap = anchors + t * 9;
    const float ax0 = ap[0], ay0 = ap[1], ax1 = ap[2], ay1 = ap[3];
    const float aarea = (ax1 - ax0 + 1.f) * (ay1 - ay0 + 1.f);

    float iwm = -1.f; int icol = 0;
    for (int col = lane; col < FEAT_W; col += 16) {
        const float sx = (float)(col * STRIDEPX);
        const float r0 = sx + ax0, r2 = sx + ax1;
        const float xx1 = fmaxf(r0, g0), xx2 = fminf(r2, g2);
        const float iw = fmaxf(xx2 - xx1 + 1.f, 0.f);
        if (iw > iwm) { iwm = iw; icol = col; }
    }
    float ihm = -1.f; int irow = 0;
    for (int row = lane; row < FEAT_H; row += 16) {
        const float sy = (float)(row * STRIDEPX);
        const float r1 = sy + ay0, r3 = sy + ay1;
        const float yy1 = fmaxf(r1, g1), yy2 = fminf(r3, g3);
        const float ih = fmaxf(yy2 - yy1 + 1.f, 0.f);
        if (ih > ihm) { ihm = ih; irow = row; }
    }
    for (int off = 8; off; off >>= 1) {
        const float ow = __shfl_down(iwm, off, 16);
        const int oc = __shfl_down(icol, off, 16);
        if (ow > iwm || (ow == iwm && oc < icol)) { iwm = ow; icol = oc; }
        const float oh = __shfl_down(ihm, off, 16);
        const int orw = __shfl_down(irow, off, 16);
        if (oh > ihm || (oh == ihm && orw < irow)) { ihm = oh; irow = orw; }
    }
    if (lane == 0) {
        const float inter = iwm * ihm;                       // verbatim iw*ih
        const float iou = inter * __builtin_amdgcn_rcpf(aarea + ag - inter);
        const int a = (irow * FEAT_W + icol) * NANC + t;
        cand[t] = valid
            ? (((unsigned long long)__float_as_uint(iou) << 32) |
               (unsigned long long)(0xFFFFFFFFu - (unsigned)a))
            : 0ull;
    }
    __syncthreads();
    if (tid == 0) {
        unsigned long long best = cand[0];
        for (int u = 1; u < NANC; ++u)
            if (cand[u] > best) best = cand[u];
        colpart[bg] = best;
    }
}

// Row pass + loss. 248 blocks x 512 thr. Thread = (col,template) pair x 8
// rows; per g: iw/agv once, per row ih + cross-mult argmax; wave-uniform
// validity + x-overlap + y-band skips (all conservative-exact: a skipped g
// could only produce inter=0, which never displaces the inter=0 seed);
// 3-deep GT prefetch. lse/best trans chains computed before the fixmap
// barrier (fixmap-independent) so their latency hides under the build.
// fixmap built in parallel AFTER the g-loop (shfl group-resolution, exact
// last-update-wins + OR); consumed only by the per-slot epilogue.
__global__ __launch_bounds__(BLK) void k_main(
    const float* __restrict__ cls, const float* __restrict__ bbox_2d,
    const float* __restrict__ bbox_3d, const float* __restrict__ gt_boxes,
    const float* __restrict__ gt_3d, const int* __restrict__ gt_labels,
    const int* __restrict__ gt_valid, const float* __restrict__ anchors,
    const float* __restrict__ means, const float* __restrict__ stds,
    const unsigned long long* __restrict__ colpart, float* __restrict__ acc,
    unsigned* __restrict__ done, float* __restrict__ out) {
#pragma clang fp contract(off)
    __shared__ float ax0_s[NANC], ay0_s[NANC], ax1_s[NANC], ay1_s[NANC];
    __shared__ float anch9[NANC * 9];
    __shared__ float4 gtb4_s[NG];     // for epilogue gathers only
    __shared__ float gt3_s[NG * 7];
    __shared__ int lbl_s[NG];
    __shared__ float mean_s[11], rstd_s[11];
    __shared__ unsigned vmask_s;
    __shared__ float red[5][BLK / 64];
    __shared__ short fixmap[NSLOT * BLK];       // 8 KB, keyed (slot j, tid)
    __shared__ unsigned fglist[NSLOT * BLK];    // 16 KB, hard-bounded
    __shared__ int nloc;

    const int tid = threadIdx.x;
    const int blk = blockIdx.x;
    const int b = blk / BPI;            // block-uniform image
    const int lblk = blk % BPI;         // local block in image
    const int ub = lblk * BLK;          // base pair-slot within image
    const int u = ub + tid;
    const bool livet = u < UREAL;       // pad tail [15840,15872) dead
    const int uc = livet ? u : (UREAL - 1);
    const int rg = uc / NPAIR;          // rowgroup 0..3
    const int p = uc - rg * NPAIR;      // pair id = col*36 + t
    const int t = p % NANC;
    const int col = p / NANC;

    // ---- staging (fixmap inputs held in registers; build deferred) ----
    for (int i = tid; i < NANC * 9; i += BLK) anch9[i] = anchors[i];
    if (tid < NANC) {
        const float* ap = anchors + tid * 9;
        ax0_s[tid] = ap[0]; ay0_s[tid] = ap[1];
        ax1_s[tid] = ap[2]; ay1_s[tid] = ap[3];
    }
    for (int i = tid; i < NG * 7; i += BLK) gt3_s[i] = gt_3d[b * NG * 7 + i];
    if (tid == 0) nloc = 0;
    int myval = 0, myba = 0, myf = 0;
    if (tid < NG) {
        const float4 q = ((const float4*)gt_boxes)[b * NG + tid];
        gtb4_s[tid] = q;
        lbl_s[tid] = gt_labels[b * NG + tid];
        myval = gt_valid[b * NG + tid];
        const unsigned long long pk = colpart[b * NG + tid]; // issued early
        const float gbest = __uint_as_float((unsigned)(pk >> 32));
        myba = myval ? (int)(0xFFFFFFFFu - (unsigned)(pk & 0xFFFFFFFFull)) : 0;
        myf = (myval && gbest >= 0.35f) ? 1 : 0;
    }
    unsigned long long bal = __ballot(tid < NG && myval);
    if (tid == 0) vmask_s = (unsigned)bal;
    if (tid < 11) { mean_s[tid] = means[tid]; rstd_s[tid] = 1.0f / stds[tid]; }
    for (int i = tid; i < NSLOT * BLK; i += BLK) fixmap[i] = -1;
    __syncthreads(); // LDS staging + fixmap clear visible
    const unsigned vmask = vmask_s;
    const size_t bbase = (size_t)b * A_TOTAL;

    // ---- per-thread geometry: x once, y per row-slot ----
    const float sx = (float)(col * STRIDEPX);
    const float r0 = sx + ax0_s[t], r2 = sx + ax1_s[t];
    const float w1 = r2 - r0 + 1.f;                  // shared exactly by rows
    float r1a[NSLOT], r3a[NSLOT], ara[NSLOT];
#pragma unroll
    for (int j = 0; j < NSLOT; ++j) {
        const float sy = (float)((rg * 8 + j) * STRIDEPX);
        r1a[j] = sy + ay0_s[t];
        r3a[j] = sy + ay1_s[t];
        ara[j] = w1 * (r3a[j] - r1a[j] + 1.f);       // == (r2-r0+1)*(r3-r1+1)
    }
    const float ylo = r1a[0];  // lowest anchor-y start across the 8 rows
    const float yhi = r3a[7];  // highest anchor-y end across the 8 rows

    // ---- early cls prefetch: 8 coalesced float4 loads hide under g-loop ----
    float4 cvk[NSLOT];
#pragma unroll
    for (int j = 0; j < NSLOT; ++j) {
        const int a = (rg * 8 + j) * NPAIR + p;
        cvk[j] = *(const float4*)(cls + (bbase + a) * NC);
    }

    // ---- argmax seed: inter=0@first-valid-g; a skipped g could only produce
    // inter=0 which never displaces the seed (0*bd > 0*den false) -> exact.
    const float4* gtb = (const float4*)gt_boxes + (size_t)b * NG;
    float bi[NSLOT], bd[NSLOT];
    int ia[NSLOT];
    if (vmask) {
        const int g0 = __builtin_ctz(vmask);
        const float4 q0 = gtb[g0];
        const float agv0 = (q0.z - q0.x + 1.f) * (q0.w - q0.y + 1.f);
#pragma unroll
        for (int j = 0; j < NSLOT; ++j) {
            bi[j] = 0.f; bd[j] = ara[j] + agv0; ia[j] = g0; // == g0, inter=0
        }
    } else {
#pragma unroll
        for (int j = 0; j < NSLOT; ++j) { bi[j] = -1.f; bd[j] = 1.f; ia[j] = 0; }
    }

    // ---- IoU argmax: iw/agv hoisted; wave-uniform x+y skips; 3-deep pf ----
    // y-band skip is conservative-exact: if q.w - ylo <= -1 then for every
    // row yy2-yy1 <= q.w - r1a[j] <= q.w - ylo <= -1 -> all ih = 0; same for
    // yhi - q.y <= -1. All-inter-0 iterations can't displace the seed.
    float4 qA = gtb[0];
    float4 qB = gtb[1 < NG ? 1 : 0];
    float4 qC = gtb[2 < NG ? 2 : 0];
#pragma unroll 4
    for (int g = 0; g < NG; ++g) {
        const float4 q = qA;                  // wave-uniform (s_load)
        qA = qB; qB = qC;
        if (g + 3 < NG) qC = gtb[g + 3];      // keep 3 loads in flight
        if ((vmask >> g) & 1u) {              // wave-uniform validity skip
            const float xx1 = fmaxf(r0, q.x), xx2 = fminf(r2, q.z);
            const float iw = fmaxf(xx2 - xx1 + 1.f, 0.f);
            const bool yposs = (q.w - ylo > -1.f) && (yhi - q.y > -1.f);
            if (__any(iw > 0.f && yposs)) {   // wave-uniform x+y skip
                const float agv = (q.z - q.x + 1.f) * (q.w - q.y + 1.f);
#pragma unroll
                for (int j = 0; j < NSLOT; ++j) {
                    const float yy1 = fmaxf(r1a[j], q.y), yy2 = fminf(r3a[j], q.w);
                    const float ih = fmaxf(yy2 - yy1 + 1.f, 0.f);
                    const float inter = iw * ih;
                    const float den = ara[j] + agv - inter;  // > 0
                    if (inter * bd[j] > bi[j] * den) {
                        bi[j] = inter; bd[j] = den; ia[j] = g;
                    }
                }
            }
        }
    }

    // ---- pre-barrier trans chains (fixmap-independent; latency hides
    // under the build + barrier): winner iou and CE log-sum-exp.
    float best[NSLOT], lse[NSLOT];
#pragma unroll
    for (int j = 0; j < NSLOT; ++j) {
        best[j] = bi[j] * __builtin_amdgcn_rcpf(bd[j]); // == r6's formula
        const float4 c4 = cvk[j];
        const float mx = fmaxf(fmaxf(c4.x, c4.y), fmaxf(c4.z, c4.w));
        const float se = __expf(c4.x - mx) + __expf(c4.y - mx) +
                         __expf(c4.z - mx) + __expf(c4.w - mx);
        lse[j] = mx + __logf(se);
    }

    // ---- deferred PARALLEL fixmap build (exact serial semantics):
    // group = lanes with equal ba (same ba <=> same idx, bijective in-block).
    // anyf = OR(forceg) over group; writer = max-g lane; code =
    // forceg[gmax] ? gmax : 32 (jax last-update-wins .set + OR .max).
    // Invalid g participates with ba=0 exactly like the jax scatter.
    if (tid < NG) {
        int anyf = 0, gmax = tid;
        for (int o = 0; o < NG; ++o) {
            const int oba = __shfl(myba, o, 64);
            const int of = __shfl(myf, o, 64);
            if (oba == myba) { anyf |= of; if (o > gmax) gmax = o; }
        }
        if (gmax == tid) { // unique writer per ba-group
            const int t_ = myba % NANC;
            const int cell = myba / NANC;
            const int col_ = cell % FEAT_W;
            const int row_ = cell / FEAT_W;
            const int pp = col_ * NANC + t_;
            const int uu = (row_ >> 3) * NPAIR + pp; // rowgroup*3960 + pair
            if ((uu >> 9) == lblk) {                 // uu/BLK == local block
                const int jj = row_ & 7;
                const int idx = jj * BLK + (uu & (BLK - 1));
                fixmap[idx] = (short)((anyf ? 0x40 : 0) | (myf ? tid : 32));
            }
        }
    }
    __syncthreads(); // fixmap final before epilogue reads

    // ---- per-slot epilogue: fixmap, CE select, fg enqueue ----
    float sum_ce = 0.f, sum_act = 0.f, sum_fg = 0.f, sum_2d = 0.f, sum_3d = 0.f;
#pragma unroll
    for (int j = 0; j < NSLOT; ++j) {
        int agt = ia[j];
        bool fg = best[j] >= 0.5f;
        const int f = fixmap[j * BLK + tid];
        if (f >= 0) {
            if (f & 0x40) fg = true;
            const int code = f & 63;
            agt = (code == 32) ? agt : code;
        }
        if (!livet) fg = false; // pad-tail threads contribute nothing
        const bool bgm = livet && (!fg) && (best[j] < 0.5f) && (best[j] >= 0.0f);
        const float active = (fg || bgm) ? 1.f : 0.f;
        const int lbl = fg ? lbl_s[agt] : 0;

        const float4 c4 = cvk[j];
        const float csel = (lbl == 0) ? c4.x : (lbl == 1) ? c4.y
                         : (lbl == 2) ? c4.z : c4.w;
        sum_ce += (lse[j] - csel) * active;
        sum_act += active;

        if (fg) { // rare: enqueue {slot,tid,agt}; regression runs below
            sum_fg += 1.f;
            const int q2 = atomicAdd(&nloc, 1); // capacity == slot count
            fglist[q2] = ((unsigned)j << 14) | ((unsigned)tid << 5) | (unsigned)agt;
        }
    }

    // ---- fg regression epilogue (identical per-anchor float math) ----
    __syncthreads(); // all appends visible, nloc final
    const int nfgl = nloc;
    for (int i = tid; i < nfgl; i += BLK) {
        const unsigned e = fglist[i];
        const int j2 = (int)(e >> 14);
        const int tid2 = (int)((e >> 5) & 511u);
        const int agt = (int)(e & 31u);
        const int u2 = ub + tid2;
        const int rg2 = u2 / NPAIR;
        const int p2 = u2 - rg2 * NPAIR;
        const int t2 = p2 % NANC;
        const int col2 = p2 / NANC;
        const int row2 = rg2 * 8 + j2;
        const int a = row2 * NPAIR + p2;
        const float sx2 = (float)(col2 * STRIDEPX);
        const float sy2 = (float)(row2 * STRIDEPX);
        const float q0 = sx2 + ax0_s[t2], q1 = sy2 + ay0_s[t2];
        const float q2_ = sx2 + ax1_s[t2], q3 = sy2 + ay1_s[t2];
        const float w = q2_ - q0 + 1.f, h = q3 - q1 + 1.f;
        const float rw = __builtin_amdgcn_rcpf(w);
        const float rh = __builtin_amdgcn_rcpf(h);
        const float cx = q0 + 0.5f * w, cy = q1 + 0.5f * h;
        const float4 Gq = gtb4_s[agt];
        const float gw = Gq.z - Gq.x + 1.f, gh = Gq.w - Gq.y + 1.f;
        const float gcx = Gq.x + 0.5f * gw, gcy = Gq.y + 0.5f * gh;
        float tt2[4];
        tt2[0] = (gcx - cx) * rw;
        tt2[1] = (gcy - cy) * rh;
        tt2[2] = __logf(gw * rw);
        tt2[3] = __logf(gh * rh);
        const float4 b2 = *(const float4*)(bbox_2d + (bbase + a) * 4);
        const float b2v[4] = {b2.x, b2.y, b2.z, b2.w};
        float l2 = 0.f;
        for (int jj = 0; jj < 4; ++jj)
            l2 += smooth_l1(b2v[jj] - (tt2[jj] - mean_s[jj]) * rstd_s[jj]);
        sum_2d += l2;
        const float* q3p = &gt3_s[agt * 7];
        const float* b3 = bbox_3d + (bbase + a) * 7;
        float tt3[7];
        tt3[0] = (q3p[0] - cx) * rw;
        tt3[1] = (q3p[1] - cy) * rh;
        tt3[2] = q3p[2] - anch9[t2 * 9 + 4];
        tt3[3] = __logf(q3p[3] * __builtin_amdgcn_rcpf(anch9[t2 * 9 + 5]));
        tt3[4] = __logf(q3p[4] * __builtin_amdgcn_rcpf(anch9[t2 * 9 + 6]));
        tt3[5] = __logf(q3p[5] * __builtin_amdgcn_rcpf(anch9[t2 * 9 + 7]));
        tt3[6] = q3p[6] - anch9[t2 * 9 + 8];
        float l3 = 0.f;
        for (int jj = 0; jj < 7; ++jj)
            l3 += smooth_l1(b3[jj] - (tt3[jj] - mean_s[4 + jj]) * rstd_s[4 + jj]);
        sum_3d += l3;
    }

    // ---- block reduce -> 5 atomics; last block finishes ----
    float vals[5] = {sum_ce, sum_act, sum_fg, sum_2d, sum_3d};
#pragma unroll
    for (int j = 0; j < 5; ++j) {
        float v = vals[j];
        for (int off = 32; off; off >>= 1) v += __shfl_down(v, off, 64);
        if ((tid & 63) == 0) red[j][tid >> 6] = v;
    }
    __syncthreads();
    if (tid == 0) {
        for (int j = 0; j < 5; ++j) {
            float s = 0.f;
            for (int w = 0; w < BLK / 64; ++w) s += red[j][w];
            atomicAdd(&acc[j], s);
        }
        __threadfence();
        const unsigned old = atomicAdd(done, 1u);
        if (old == G2 - 1) {
            const float a0 = atomicAdd(&acc[0], 0.f);
            const float a1 = atomicAdd(&acc[1], 0.f);
            const float a2 = atomicAdd(&acc[2], 0.f);
            const float a3 = atomicAdd(&acc[3], 0.f);
            const float a4 = atomicAdd(&acc[4], 0.f);
            const float nact = fmaxf(a1, 1.f);
            const float nfg = fmaxf(a2, 1.f);
            out[0] = a0 / nact + a3 / nfg + a4 / nfg;
        }
    }
}

extern "C" void kernel_launch(void* const* d_in, const int* in_sizes, int n_in,
                              void* d_out, int out_size, void* d_ws, size_t ws_size,
                              hipStream_t stream) {
    const float* cls      = (const float*)d_in[0];
    const float* bbox_2d  = (const float*)d_in[1];
    const float* bbox_3d  = (const float*)d_in[2];
    const float* gt_boxes = (const float*)d_in[3];
    const float* gt_3d    = (const float*)d_in[4];
    const int*   gt_labels= (const int*)d_in[5];
    const int*   gt_valid = (const int*)d_in[6];
    const float* anchors  = (const float*)d_in[7];
    const float* means    = (const float*)d_in[8];
    const float* stds     = (const float*)d_in[9];

    unsigned long long* colpart = (unsigned long long*)d_ws;  // 2 KB @0
    float* acc = (float*)((char*)d_ws + 8192);
    unsigned* done = (unsigned*)((char*)d_ws + 8192 + 32);
    float* out = (float*)d_out;

    k_colpass<<<NB * NG, CPB, 0, stream>>>(gt_boxes, gt_valid, anchors,
                                           colpart, acc, done);
    k_main<<<G2, BLK, 0, stream>>>(cls, bbox_2d, bbox_3d, gt_boxes, gt_3d,
                                   gt_labels, gt_valid, anchors, means, stds,
                                   colpart, acc, done, out);
}

// Round 13
// 131.909 us; speedup vs baseline: 1.0215x; 1.0215x over previous
//
#include <hip/hip_runtime.h>

#define FEAT_H 32
#define FEAT_W 110
#define NCELL (FEAT_H * FEAT_W) /* 3520 */
#define STRIDEPX 16
#define NB 8
#define NG 32
#define NANC 36
#define NC 4
#define A_TOTAL (NCELL * NANC) /* 126720 */

#define CPB 576              /* colpass: 36 anchor-templates x 16 lanes */

#define BLK 512              /* k_main threads/block (r9/r11 shape: best measured) */
#define BPI 31               /* blocks per image (15872/512) */
#define G2 (NB * BPI)        /* 248 blocks */
#define NPAIR 3960           /* (col,template) pairs per image = 110*36 */
#define UREAL 15840          /* real pair-slots per image = 3960*4 rowgroups */
#define NSLOT 8              /* rows per thread (rowgroup = 8 rows) */

__device__ __forceinline__ float smooth_l1(float x) {
    float ax = fabsf(x);
    return ax < 1.f ? 0.5f * ax * ax : ax - 0.5f;
}

// ws: colpart[256] u64 @0 (2 KB), acc[8] f32 @8192, done u32 @8224.

// LESSONS (rounds 2-12, final):
// (a) no min-waves arg to __launch_bounds__ (r2/r4: ~150 MB scratch spill).
// (b) ~90 us of e2e is the harness's 256 MiB workspace re-poison fills
//     (77-82% of HBM peak — their own roofline); colpass ~3.5 us; k_main
//     ~38 us (~12 us dispatch ramp + ~26 us latency-bound body).
// (c) BLK=512/BPI=31 is the proven shape (r10's 256-thr split regressed).
// (d) r12's y-band skip + pre-barrier trans hoist were within-noise
//     neutral -> reverted; this is the exact r11 best-measured kernel.
// (e) k_main plateaued across 5 mechanism classes (occupancy, ILP, work
//     reduction, wave-skips, latency hoisting); remaining levers <= noise.

// Factorized column-max pass (r5, exact): IoU monotone in inter and
// inter = iw(col)*ih(row) separable -> per (t,g) the 3520-cell max is
// max_col(iw)*max_row(ih); first-occurrence argmax = (min row of ih-max,
// min col of iw-max), lexicographic like the cell index. Float exprs
// verbatim -> packed (iou<<32 | ~a) bit-identical to the full scan.
__global__ __launch_bounds__(CPB) void k_colpass(
    const float* __restrict__ gt_boxes, const int* __restrict__ gt_valid,
    const float* __restrict__ anchors, unsigned long long* __restrict__ colpart,
    float* __restrict__ acc, unsigned* __restrict__ done) {
#pragma clang fp contract(off)
    __shared__ unsigned long long cand[NANC];
    const int tid = threadIdx.x;
    const int bg = blockIdx.x; // column (b*NG+g), 0..255
    if (bg == 0) { // ws is 0xAA-poisoned each call
        if (tid < 8) acc[tid] = 0.f;
        if (tid == 8) *done = 0u;
    }
    const int t = tid >> 4;    // anchor template 0..35
    const int lane = tid & 15; // 16 lanes per template
    const int valid = gt_valid[bg];
    const float g0 = gt_boxes[bg * 4 + 0], g1 = gt_boxes[bg * 4 + 1];
    const float g2 = gt_boxes[bg * 4 + 2], g3 = gt_boxes[bg * 4 + 3];
    const float ag = (g2 - g0 + 1.f) * (g3 - g1 + 1.f);
    const float* ap = anchors + t * 9;
    const float ax0 = ap[0], ay0 = ap[1], ax1 = ap[2], ay1 = ap[3];
    const float aarea = (ax1 - ax0 + 1.f) * (ay1 - ay0 + 1.f);

    float iwm = -1.f; int icol = 0;
    for (int col = lane; col < FEAT_W; col += 16) {
        const float sx = (float)(col * STRIDEPX);
        const float r0 = sx + ax0, r2 = sx + ax1;
        const float xx1 = fmaxf(r0, g0), xx2 = fminf(r2, g2);
        const float iw = fmaxf(xx2 - xx1 + 1.f, 0.f);
        if (iw > iwm) { iwm = iw; icol = col; }
    }
    float ihm = -1.f; int irow = 0;
    for (int row = lane; row < FEAT_H; row += 16) {
        const float sy = (float)(row * STRIDEPX);
        const float r1 = sy + ay0, r3 = sy + ay1;
        const float yy1 = fmaxf(r1, g1), yy2 = fminf(r3, g3);
        const float ih = fmaxf(yy2 - yy1 + 1.f, 0.f);
        if (ih > ihm) { ihm = ih; irow = row; }
    }
    for (int off = 8; off; off >>= 1) {
        const float ow = __shfl_down(iwm, off, 16);
        const int oc = __shfl_down(icol, off, 16);
        if (ow > iwm || (ow == iwm && oc < icol)) { iwm = ow; icol = oc; }
        const float oh = __shfl_down(ihm, off, 16);
        const int orw = __shfl_down(irow, off, 16);
        if (oh > ihm || (oh == ihm && orw < irow)) { ihm = oh; irow = orw; }
    }
    if (lane == 0) {
        const float inter = iwm * ihm;                       // verbatim iw*ih
        const float iou = inter * __builtin_amdgcn_rcpf(aarea + ag - inter);
        const int a = (irow * FEAT_W + icol) * NANC + t;
        cand[t] = valid
            ? (((unsigned long long)__float_as_uint(iou) << 32) |
               (unsigned long long)(0xFFFFFFFFu - (unsigned)a))
            : 0ull;
    }
    __syncthreads();
    if (tid == 0) {
        unsigned long long best = cand[0];
        for (int u = 1; u < NANC; ++u)
            if (cand[u] > best) best = cand[u];
        colpart[bg] = best;
    }
}

// Row pass + loss. 248 blocks x 512 thr (r9 shape). Thread = (col,template)
// pair x 8 rows; per g: iw/agv once, per row ih + cross-mult argmax;
// wave-uniform validity+x-overlap skips (seed = inter=0@first-valid-g,
// bit-exact); 3-deep GT prefetch. fixmap: colpart loaded in staging
// (registers, lanes 0..31), built in parallel AFTER the g-loop (shfl
// group-resolution, exact last-update-wins + OR) so its latency hides
// under compute; consumed only by the per-slot epilogue.
__global__ __launch_bounds__(BLK) void k_main(
    const float* __restrict__ cls, const float* __restrict__ bbox_2d,
    const float* __restrict__ bbox_3d, const float* __restrict__ gt_boxes,
    const float* __restrict__ gt_3d, const int* __restrict__ gt_labels,
    const int* __restrict__ gt_valid, const float* __restrict__ anchors,
    const float* __restrict__ means, const float* __restrict__ stds,
    const unsigned long long* __restrict__ colpart, float* __restrict__ acc,
    unsigned* __restrict__ done, float* __restrict__ out) {
#pragma clang fp contract(off)
    __shared__ float ax0_s[NANC], ay0_s[NANC], ax1_s[NANC], ay1_s[NANC];
    __shared__ float anch9[NANC * 9];
    __shared__ float4 gtb4_s[NG];     // for epilogue gathers only
    __shared__ float gt3_s[NG * 7];
    __shared__ int lbl_s[NG];
    __shared__ float mean_s[11], rstd_s[11];
    __shared__ unsigned vmask_s;
    __shared__ float red[5][BLK / 64];
    __shared__ short fixmap[NSLOT * BLK];       // 8 KB, keyed (slot j, tid)
    __shared__ unsigned fglist[NSLOT * BLK];    // 16 KB, hard-bounded
    __shared__ int nloc;

    const int tid = threadIdx.x;
    const int blk = blockIdx.x;
    const int b = blk / BPI;            // block-uniform image
    const int lblk = blk % BPI;         // local block in image
    const int ub = lblk * BLK;          // base pair-slot within image
    const int u = ub + tid;
    const bool livet = u < UREAL;       // pad tail [15840,15872) dead
    const int uc = livet ? u : (UREAL - 1);
    const int rg = uc / NPAIR;          // rowgroup 0..3
    const int p = uc - rg * NPAIR;      // pair id = col*36 + t
    const int t = p % NANC;
    const int col = p / NANC;

    // ---- staging (fixmap inputs held in registers; build deferred) ----
    for (int i = tid; i < NANC * 9; i += BLK) anch9[i] = anchors[i];
    if (tid < NANC) {
        const float* ap = anchors + tid * 9;
        ax0_s[tid] = ap[0]; ay0_s[tid] = ap[1];
        ax1_s[tid] = ap[2]; ay1_s[tid] = ap[3];
    }
    for (int i = tid; i < NG * 7; i += BLK) gt3_s[i] = gt_3d[b * NG * 7 + i];
    if (tid == 0) nloc = 0;
    int myval = 0, myba = 0, myf = 0;
    if (tid < NG) {
        const float4 q = ((const float4*)gt_boxes)[b * NG + tid];
        gtb4_s[tid] = q;
        lbl_s[tid] = gt_labels[b * NG + tid];
        myval = gt_valid[b * NG + tid];
        const unsigned long long pk = colpart[b * NG + tid]; // issued early
        const float gbest = __uint_as_float((unsigned)(pk >> 32));
        myba = myval ? (int)(0xFFFFFFFFu - (unsigned)(pk & 0xFFFFFFFFull)) : 0;
        myf = (myval && gbest >= 0.35f) ? 1 : 0;
    }
    unsigned long long bal = __ballot(tid < NG && myval);
    if (tid == 0) vmask_s = (unsigned)bal;
    if (tid < 11) { mean_s[tid] = means[tid]; rstd_s[tid] = 1.0f / stds[tid]; }
    for (int i = tid; i < NSLOT * BLK; i += BLK) fixmap[i] = -1;
    __syncthreads(); // LDS staging + fixmap clear visible
    const unsigned vmask = vmask_s;
    const size_t bbase = (size_t)b * A_TOTAL;

    // ---- per-thread geometry: x once, y per row-slot ----
    const float sx = (float)(col * STRIDEPX);
    const float r0 = sx + ax0_s[t], r2 = sx + ax1_s[t];
    const float w1 = r2 - r0 + 1.f;                  // shared exactly by rows
    float r1a[NSLOT], r3a[NSLOT], ara[NSLOT];
#pragma unroll
    for (int j = 0; j < NSLOT; ++j) {
        const float sy = (float)((rg * 8 + j) * STRIDEPX);
        r1a[j] = sy + ay0_s[t];
        r3a[j] = sy + ay1_s[t];
        ara[j] = w1 * (r3a[j] - r1a[j] + 1.f);       // == (r2-r0+1)*(r3-r1+1)
    }

    // ---- early cls prefetch: 8 coalesced float4 loads hide under g-loop ----
    float4 cvk[NSLOT];
#pragma unroll
    for (int j = 0; j < NSLOT; ++j) {
        const int a = (rg * 8 + j) * NPAIR + p;
        cvk[j] = *(const float4*)(cls + (bbase + a) * NC);
    }

    // ---- argmax seed: inter=0@first-valid-g; a skipped g could only produce
    // inter=0 which never displaces the seed (0*bd > 0*den false) -> exact.
    const float4* gtb = (const float4*)gt_boxes + (size_t)b * NG;
    float bi[NSLOT], bd[NSLOT];
    int ia[NSLOT];
    if (vmask) {
        const int g0 = __builtin_ctz(vmask);
        const float4 q0 = gtb[g0];
        const float agv0 = (q0.z - q0.x + 1.f) * (q0.w - q0.y + 1.f);
#pragma unroll
        for (int j = 0; j < NSLOT; ++j) {
            bi[j] = 0.f; bd[j] = ara[j] + agv0; ia[j] = g0; // == g0, inter=0
        }
    } else {
#pragma unroll
        for (int j = 0; j < NSLOT; ++j) { bi[j] = -1.f; bd[j] = 1.f; ia[j] = 0; }
    }

    // ---- IoU argmax: iw/agv hoisted; wave-uniform skips; 3-deep prefetch ----
    float4 qA = gtb[0];
    float4 qB = gtb[1 < NG ? 1 : 0];
    float4 qC = gtb[2 < NG ? 2 : 0];
#pragma unroll 4
    for (int g = 0; g < NG; ++g) {
        const float4 q = qA;                  // wave-uniform (s_load)
        qA = qB; qB = qC;
        if (g + 3 < NG) qC = gtb[g + 3];      // keep 3 loads in flight
        if ((vmask >> g) & 1u) {              // wave-uniform validity skip
            const float xx1 = fmaxf(r0, q.x), xx2 = fminf(r2, q.z);
            const float iw = fmaxf(xx2 - xx1 + 1.f, 0.f);
            if (__any(iw > 0.f)) {            // wave-uniform x-overlap skip
                const float agv = (q.z - q.x + 1.f) * (q.w - q.y + 1.f);
#pragma unroll
                for (int j = 0; j < NSLOT; ++j) {
                    const float yy1 = fmaxf(r1a[j], q.y), yy2 = fminf(r3a[j], q.w);
                    const float ih = fmaxf(yy2 - yy1 + 1.f, 0.f);
                    const float inter = iw * ih;
                    const float den = ara[j] + agv - inter;  // > 0
                    if (inter * bd[j] > bi[j] * den) {
                        bi[j] = inter; bd[j] = den; ia[j] = g;
                    }
                }
            }
        }
    }

    // ---- deferred PARALLEL fixmap build (exact serial semantics):
    // group = lanes with equal ba (same ba <=> same idx, bijective in-block).
    // anyf = OR(forceg) over group; writer = max-g lane; code =
    // forceg[gmax] ? gmax : 32 (jax last-update-wins .set + OR .max).
    // Invalid g participates with ba=0 exactly like the jax scatter.
    if (tid < NG) {
        int anyf = 0, gmax = tid;
        for (int o = 0; o < NG; ++o) {
            const int oba = __shfl(myba, o, 64);
            const int of = __shfl(myf, o, 64);
            if (oba == myba) { anyf |= of; if (o > gmax) gmax = o; }
        }
        if (gmax == tid) { // unique writer per ba-group
            const int t_ = myba % NANC;
            const int cell = myba / NANC;
            const int col_ = cell % FEAT_W;
            const int row_ = cell / FEAT_W;
            const int pp = col_ * NANC + t_;
            const int uu = (row_ >> 3) * NPAIR + pp; // rowgroup*3960 + pair
            if ((uu >> 9) == lblk) {                 // uu/BLK == local block
                const int jj = row_ & 7;
                const int idx = jj * BLK + (uu & (BLK - 1));
                fixmap[idx] = (short)((anyf ? 0x40 : 0) | (myf ? tid : 32));
            }
        }
    }
    __syncthreads(); // fixmap final before epilogue reads

    // ---- per-slot epilogue: winner iou, fixmap, CE, fg enqueue ----
    float sum_ce = 0.f, sum_act = 0.f, sum_fg = 0.f, sum_2d = 0.f, sum_3d = 0.f;
#pragma unroll
    for (int j = 0; j < NSLOT; ++j) {
        // winner iou: same formula as r6's inter*rcpf(den) -> same value
        const float best = bi[j] * __builtin_amdgcn_rcpf(bd[j]);
        int agt = ia[j];
        bool fg = best >= 0.5f;
        const int f = fixmap[j * BLK + tid];
        if (f >= 0) {
            if (f & 0x40) fg = true;
            const int code = f & 63;
            agt = (code == 32) ? agt : code;
        }
        if (!livet) fg = false; // pad-tail threads contribute nothing
        const bool bgm = livet && (!fg) && (best < 0.5f) && (best >= 0.0f);
        const float active = (fg || bgm) ? 1.f : 0.f;
        const int lbl = fg ? lbl_s[agt] : 0;

        const float4 c4 = cvk[j];
        const float mx = fmaxf(fmaxf(c4.x, c4.y), fmaxf(c4.z, c4.w));
        const float se = __expf(c4.x - mx) + __expf(c4.y - mx) +
                         __expf(c4.z - mx) + __expf(c4.w - mx);
        const float lse = mx + __logf(se);
        const float csel = (lbl == 0) ? c4.x : (lbl == 1) ? c4.y
                         : (lbl == 2) ? c4.z : c4.w;
        sum_ce += (lse - csel) * active;
        sum_act += active;

        if (fg) { // rare: enqueue {slot,tid,agt}; regression runs below
            sum_fg += 1.f;
            const int q2 = atomicAdd(&nloc, 1); // capacity == slot count
            fglist[q2] = ((unsigned)j << 14) | ((unsigned)tid << 5) | (unsigned)agt;
        }
    }

    // ---- fg regression epilogue (identical per-anchor float math) ----
    __syncthreads(); // all appends visible, nloc final
    const int nfgl = nloc;
    for (int i = tid; i < nfgl; i += BLK) {
        const unsigned e = fglist[i];
        const int j2 = (int)(e >> 14);
        const int tid2 = (int)((e >> 5) & 511u);
        const int agt = (int)(e & 31u);
        const int u2 = ub + tid2;
        const int rg2 = u2 / NPAIR;
        const int p2 = u2 - rg2 * NPAIR;
        const int t2 = p2 % NANC;
        const int col2 = p2 / NANC;
        const int row2 = rg2 * 8 + j2;
        const int a = row2 * NPAIR + p2;
        const float sx2 = (float)(col2 * STRIDEPX);
        const float sy2 = (float)(row2 * STRIDEPX);
        const float q0 = sx2 + ax0_s[t2], q1 = sy2 + ay0_s[t2];
        const float q2_ = sx2 + ax1_s[t2], q3 = sy2 + ay1_s[t2];
        const float w = q2_ - q0 + 1.f, h = q3 - q1 + 1.f;
        const float rw = __builtin_amdgcn_rcpf(w);
        const float rh = __builtin_amdgcn_rcpf(h);
        const float cx = q0 + 0.5f * w, cy = q1 + 0.5f * h;
        const float4 Gq = gtb4_s[agt];
        const float gw = Gq.z - Gq.x + 1.f, gh = Gq.w - Gq.y + 1.f;
        const float gcx = Gq.x + 0.5f * gw, gcy = Gq.y + 0.5f * gh;
        float tt2[4];
        tt2[0] = (gcx - cx) * rw;
        tt2[1] = (gcy - cy) * rh;
        tt2[2] = __logf(gw * rw);
        tt2[3] = __logf(gh * rh);
        const float4 b2 = *(const float4*)(bbox_2d + (bbase + a) * 4);
        const float b2v[4] = {b2.x, b2.y, b2.z, b2.w};
        float l2 = 0.f;
        for (int jj = 0; jj < 4; ++jj)
            l2 += smooth_l1(b2v[jj] - (tt2[jj] - mean_s[jj]) * rstd_s[jj]);
        sum_2d += l2;
        const float* q3p = &gt3_s[agt * 7];
        const float* b3 = bbox_3d + (bbase + a) * 7;
        float tt3[7];
        tt3[0] = (q3p[0] - cx) * rw;
        tt3[1] = (q3p[1] - cy) * rh;
        tt3[2] = q3p[2] - anch9[t2 * 9 + 4];
        tt3[3] = __logf(q3p[3] * __builtin_amdgcn_rcpf(anch9[t2 * 9 + 5]));
        tt3[4] = __logf(q3p[4] * __builtin_amdgcn_rcpf(anch9[t2 * 9 + 6]));
        tt3[5] = __logf(q3p[5] * __builtin_amdgcn_rcpf(anch9[t2 * 9 + 7]));
        tt3[6] = q3p[6] - anch9[t2 * 9 + 8];
        float l3 = 0.f;
        for (int jj = 0; jj < 7; ++jj)
            l3 += smooth_l1(b3[jj] - (tt3[jj] - mean_s[4 + jj]) * rstd_s[4 + jj]);
        sum_3d += l3;
    }

    // ---- block reduce -> 5 atomics; last block finishes ----
    float vals[5] = {sum_ce, sum_act, sum_fg, sum_2d, sum_3d};
#pragma unroll
    for (int j = 0; j < 5; ++j) {
        float v = vals[j];
        for (int off = 32; off; off >>= 1) v += __shfl_down(v, off, 64);
        if ((tid & 63) == 0) red[j][tid >> 6] = v;
    }
    __syncthreads();
    if (tid == 0) {
        for (int j = 0; j < 5; ++j) {
            float s = 0.f;
            for (int w = 0; w < BLK / 64; ++w) s += red[j][w];
            atomicAdd(&acc[j], s);
        }
        __threadfence();
        const unsigned old = atomicAdd(done, 1u);
        if (old == G2 - 1) {
            const float a0 = atomicAdd(&acc[0], 0.f);
            const float a1 = atomicAdd(&acc[1], 0.f);
            const float a2 = atomicAdd(&acc[2], 0.f);
            const float a3 = atomicAdd(&acc[3], 0.f);
            const float a4 = atomicAdd(&acc[4], 0.f);
            const float nact = fmaxf(a1, 1.f);
            const float nfg = fmaxf(a2, 1.f);
            out[0] = a0 / nact + a3 / nfg + a4 / nfg;
        }
    }
}

extern "C" void kernel_launch(void* const* d_in, const int* in_sizes, int n_in,
                              void* d_out, int out_size, void* d_ws, size_t ws_size,
                              hipStream_t stream) {
    const float* cls      = (const float*)d_in[0];
    const float* bbox_2d  = (const float*)d_in[1];
    const float* bbox_3d  = (const float*)d_in[2];
    const float* gt_boxes = (const float*)d_in[3];
    const float* gt_3d    = (const float*)d_in[4];
    const int*   gt_labels= (const int*)d_in[5];
    const int*   gt_valid = (const int*)d_in[6];
    const float* anchors  = (const float*)d_in[7];
    const float* means    = (const float*)d_in[8];
    const float* stds     = (const float*)d_in[9];

    unsigned long long* colpart = (unsigned long long*)d_ws;  // 2 KB @0
    float* acc = (float*)((char*)d_ws + 8192);
    unsigned* done = (unsigned*)((char*)d_ws + 8192 + 32);
    float* out = (float*)d_out;

    k_colpass<<<NB * NG, CPB, 0, stream>>>(gt_boxes, gt_valid, anchors,
                                           colpart, acc, done);
    k_main<<<G2, BLK, 0, stream>>>(cls, bbox_2d, bbox_3d, gt_boxes, gt_3d,
                                   gt_labels, gt_valid, anchors, means, stds,
                                   colpart, acc, done, out);
}